// Round 1
// baseline (179.500 us; speedup 1.0000x reference)
//
#include <hip/hip_runtime.h>
#include <math.h>

// Problem constants (match reference)
constexpr int   B       = 2048;
constexpr int   P       = 4;
constexpr int   D       = 256;       // K of the GEMM
constexpr int   NNEG    = 32768;
constexpr int   NTILES  = NNEG / 64; // per-row exp2-sum partials (64-col patches)
constexpr float TEMP    = 0.05f;
constexpr float ALPHA   = 0.1f;
constexpr float EPS     = 1e-12f;
constexpr float INV_T   = 1.0f / TEMP;
// A-side rows are pre-scaled by (1/T)*log2(e) so the MFMA accumulator is
// directly q = sim/T * log2(e), and exp(sim/T) = exp2(q).  |q| <= ~30 so no
// max-tracking is needed, and 28.85 << 448 (fp8 e4m3 max) so the scale is
// fp8-safe; fp relative precision is scale-invariant.
constexpr float SCALE_Q = 28.853900817779268f;

typedef float f32x4 __attribute__((ext_vector_type(4)));
typedef int   i32x8 __attribute__((ext_vector_type(8)));

// fp32 -> bf16 (RNE), bit-level
__device__ inline unsigned short f2bf(float f) {
  unsigned int u = __float_as_uint(f);
  u = (u + 0x7fffu + ((u >> 16) & 1u)) >> 16;
  return (unsigned short)u;
}
// bf16 bits -> fp32
__device__ inline float bf2f(unsigned short u) {
  return __uint_as_float((unsigned int)u << 16);
}

// ---------------------------------------------------------------------------
// FP8 FRAGMENT-MAJOR layout: element (row, k) of a [R x 256] fp8 matrix is at
// BYTE index  p*4096 + c*512 + q*128 + r*8 + j
// where p=row>>4 (16-row panel, 4096 B contiguous), r=row&15, c=k>>5
// (32-k chunk), q=(k>>3)&3, j=k&7.  Fragment (p,c) = 512 contiguous bytes;
// lane l=r+16q reads its 8 B at byte offset l*8.  k identically permuted for
// A and B, so any consistent chunk ordering fed to the MFMA is exact.
// ---------------------------------------------------------------------------

// ---------------------------------------------------------------------------
// Kernel 1 (fused prep).  Two block ranges:
//  [0, NPANEL): one block per 16-row panel.  Phase 1: wave w normalizes rows
//    w*4..w*4+3 into an LDS bf16 tile (stride 264).  Phase 2 (after barrier):
//    thread t converts to fp8 and writes panel BYTES [t*16,+16) — the 4 KB
//    fp8 panel image is one contiguous coalesced stream.
//  [NPANEL, ...): possim, one wave per (b,j) pair, exact fp32.
// ---------------------------------------------------------------------------
constexpr int NPANEL = (B + NNEG) / 16;      // 2176
constexpr int LSTR   = 264;                  // LDS row stride in ushorts

__global__ __launch_bounds__(256) void prep_kernel(
    const float* __restrict__ a,
    const float* __restrict__ pzx,
    const float* __restrict__ n,
    unsigned char* __restrict__ a_f8,
    unsigned char* __restrict__ n_f8,
    float* __restrict__ pos_sim,
    float* __restrict__ loss_acc,
    unsigned int* __restrict__ ticket) {
  if (blockIdx.x == 0 && threadIdx.x == 0) { *loss_acc = 0.0f; *ticket = 0u; }
  const int id   = blockIdx.x;
  const int tid  = threadIdx.x;
  const int wave = tid >> 6;
  const int lane = tid & 63;

  if (id < NPANEL) {
    __shared__ __align__(16) unsigned short sm[16 * LSTR];
    const float* src; unsigned char* dst; int prow; float post;
    if (id < B / 16) { src = a; dst = a_f8; prow = id;          post = SCALE_Q; }
    else             { src = n; dst = n_f8; prow = id - B / 16; post = 1.0f; }

    // Phase 1: normalize rows into LDS (bf16).
#pragma unroll
    for (int rr = 0; rr < 4; rr++) {
      const int r = wave * 4 + rr;                       // 0..15
      float4 v = ((const float4*)(src + ((size_t)prow * 16 + r) * D))[lane];
      float ss = v.x * v.x + v.y * v.y + v.z * v.z + v.w * v.w;
#pragma unroll
      for (int off = 32; off > 0; off >>= 1) ss += __shfl_xor(ss, off, 64);
      float inv = post / fmaxf(sqrtf(ss), EPS);
      ushort4 o;
      o.x = f2bf(v.x * inv); o.y = f2bf(v.y * inv);
      o.z = f2bf(v.z * inv); o.w = f2bf(v.w * inv);
      *(ushort4*)&sm[r * LSTR + lane * 4] = o;
    }
    __syncthreads();

    // Phase 2: thread t emits fp8 panel bytes [t*16,+16) as one uint4 store.
    const int r1 = (2 * tid) & 15;
    const int r2 = (2 * tid + 1) & 15;
    const int k0 = (tid >> 5) * 32 + ((tid >> 3) & 3) * 8;
    const unsigned short* s1 = &sm[r1 * LSTR + k0];
    const unsigned short* s2 = &sm[r2 * LSTR + k0];
    uint4 ov;
    {
      int w0 = __builtin_amdgcn_cvt_pk_fp8_f32(bf2f(s1[0]), bf2f(s1[1]), 0, false);
      w0     = __builtin_amdgcn_cvt_pk_fp8_f32(bf2f(s1[2]), bf2f(s1[3]), w0, true);
      int w1 = __builtin_amdgcn_cvt_pk_fp8_f32(bf2f(s1[4]), bf2f(s1[5]), 0, false);
      w1     = __builtin_amdgcn_cvt_pk_fp8_f32(bf2f(s1[6]), bf2f(s1[7]), w1, true);
      int w2 = __builtin_amdgcn_cvt_pk_fp8_f32(bf2f(s2[0]), bf2f(s2[1]), 0, false);
      w2     = __builtin_amdgcn_cvt_pk_fp8_f32(bf2f(s2[2]), bf2f(s2[3]), w2, true);
      int w3 = __builtin_amdgcn_cvt_pk_fp8_f32(bf2f(s2[4]), bf2f(s2[5]), 0, false);
      w3     = __builtin_amdgcn_cvt_pk_fp8_f32(bf2f(s2[6]), bf2f(s2[7]), w3, true);
      ov.x = (unsigned)w0; ov.y = (unsigned)w1;
      ov.z = (unsigned)w2; ov.w = (unsigned)w3;
    }
    *(uint4*)(dst + (size_t)prow * 4096 + tid * 16) = ov;
  } else {
    int pw = (id - NPANEL) * 4 + wave;   // 0..B*P-1
    if (pw >= B * P) return;
    int b = pw >> 2;                     // P == 4
    float4 av = ((const float4*)(a + (size_t)b * D))[lane];
    float4 pv = ((const float4*)(pzx + (size_t)pw * D))[lane];
    float d  = av.x * pv.x + av.y * pv.y + av.z * pv.z + av.w * pv.w;
    float sa = av.x * av.x + av.y * av.y + av.z * av.z + av.w * av.w;
    float sp = pv.x * pv.x + pv.y * pv.y + pv.z * pv.z + pv.w * pv.w;
#pragma unroll
    for (int off = 32; off > 0; off >>= 1) {
      d  += __shfl_xor(d, off, 64);
      sa += __shfl_xor(sa, off, 64);
      sp += __shfl_xor(sp, off, 64);
    }
    if (lane == 0) {
      float inva = 1.0f / fmaxf(sqrtf(sa), EPS);
      float invp = 1.0f / fmaxf(sqrtf(sp), EPS);
      pos_sim[pw] = d * inva * invp * INV_T;
    }
  }
}

// ---------------------------------------------------------------------------
// Kernel 2: MX-scaled fp8 MFMA GEMM (mfma_scale_f32_16x16x128_f8f6f4 with
// unit e8m0 scales = bit-identical fp8 math at 2x the non-scaled fp8 rate:
// 4661 TF vs 2047 TF measured) fused with exp2-sum partials.
// Block = 64x256 tile, 4 waves; wave w owns a 64x64 col-patch (4x4 of 16x16
// tiles, acc = 64 VGPR).  A-tile 16 KB staged via 4 global_load_lds
// instructions per wave; one barrier total; zero barriers in the K-loop.
// K=256 = two K=128 halves; per half: 16 global b64 B-loads + 16 ds_read_b64
// A-loads (conflict-free at stride 8 B) + 16 MFMA.  Same bytes moved as the
// 16x16x32 version, 1/4 the MFMA instructions, 1/2 the MFMA cycles.
// A and B are fed the identical chunk ordering (k = 128h+32q+8t+j at operand
// byte 8q+j), so the dot product is exact for any HW lane->k layout; scales
// are all 0x7f (=2^0) so scale-block assignment is irrelevant.
// XCD swizzle: id&7 -> xcd owns 16-nblk strip (1 MB N fp8) + A (0.5 MB).
// Epilogue: acc holds q = sim/T*log2e; 16-lane shuffle exp2-sum -> part_s.
// ---------------------------------------------------------------------------
constexpr int BM = 64, BN = 256;

__global__ __launch_bounds__(256, 4) void negsim_mfma_kernel(
    const unsigned char* __restrict__ Af,   // fp8 frag-major [B][256]
    const unsigned char* __restrict__ Nf,   // fp8 frag-major [NNEG][256]
    float* __restrict__ part_s) {           // [B][NTILES]
  __shared__ __align__(16) unsigned char As[32 * 512];  // 16 KB

  const int tid  = threadIdx.x;
  const int wave = tid >> 6;   // 0..3 = N-direction 64-col patch
  const int lane = tid & 63;

  const int id   = blockIdx.x;
  const int xcd  = id & 7;
  const int j    = id >> 3;              // 0..511
  const int nblk = xcd * 16 + (j & 15);  // 0..127
  const int mblk = j >> 4;               // 0..31
  const int m0   = mblk * BM;
  const int n0   = nblk * BN;

  // ---- stage A-tile once: instr s = wave*4+t covers LDS [s*1024, +1024)
  //      = frags (p = wave, c = 2t, 2t+1); contiguous in global too. ----
#pragma unroll
  for (int t = 0; t < 4; t++) {
    const int s = wave * 4 + t;
    __builtin_amdgcn_global_load_lds(
        (const __attribute__((address_space(1))) unsigned int*)
            (Af + (size_t)((m0 >> 4) + wave) * 4096 + t * 1024 + lane * 16),
        (__attribute__((address_space(3))) unsigned int*)(As + s * 1024 + lane * 16),
        16, 0, 0);
  }
  __syncthreads();   // the kernel's only barrier (drains the staging loads)

  // ---- K-loop: A from LDS (b64 reads), B direct from global (L2-resident;
  //      per-ni base regs + imm offsets, all offsets < 4096) ----
  const unsigned char* Bp = Nf + (size_t)((n0 >> 4) + wave * 4) * 4096 + lane * 8;

  f32x4 acc[4][4] = {};

#pragma unroll
  for (int h = 0; h < 2; h++) {
    i32x8 bf[4];
#pragma unroll
    for (int ni = 0; ni < 4; ni++) {
      const unsigned char* bpi = Bp + (size_t)ni * 4096 + h * 2048;
#pragma unroll
      for (int q = 0; q < 4; q++) {
        int2 v = *(const int2*)(bpi + q * 512);
        bf[ni][2 * q]     = v.x;
        bf[ni][2 * q + 1] = v.y;
      }
    }
#pragma unroll
    for (int mi = 0; mi < 4; mi++) {
      i32x8 af;
#pragma unroll
      for (int q = 0; q < 4; q++) {
        int2 v = *(const int2*)&As[(mi * 8 + h * 4 + q) * 512 + lane * 8];
        af[2 * q]     = v.x;
        af[2 * q + 1] = v.y;
      }
#pragma unroll
      for (int ni = 0; ni < 4; ni++)
        acc[mi][ni] = __builtin_amdgcn_mfma_scale_f32_16x16x128_f8f6f4(
            af, bf[ni], acc[mi][ni],
            0, 0,                       // cbsz/blgp: FP8 e4m3 for A and B
            0, 0x7f7f7f7f,              // scale_a = 1.0 (e8m0 127), any opsel
            0, 0x7f7f7f7f);             // scale_b = 1.0
    }
  }

  // Epilogue: C/D layout row = mi*16 + (lane>>4)*4 + rr, col = ni*16+(lane&15)
  // (dtype/shape-determined on gfx950, same as 16x16x32).
#pragma unroll
  for (int mi = 0; mi < 4; mi++) {
#pragma unroll
    for (int rr = 0; rr < 4; rr++) {
      float s = __builtin_amdgcn_exp2f(acc[mi][0][rr]) +
                __builtin_amdgcn_exp2f(acc[mi][1][rr]) +
                __builtin_amdgcn_exp2f(acc[mi][2][rr]) +
                __builtin_amdgcn_exp2f(acc[mi][3][rr]);
#pragma unroll
      for (int off = 1; off < 16; off <<= 1) s += __shfl_xor(s, off, 64);
      if ((lane & 15) == 0) {
        int row = m0 + mi * 16 + (lane >> 4) * 4 + rr;
        part_s[(size_t)row * NTILES + (nblk * 4 + wave)] = s;
      }
    }
  }
}

// ---------------------------------------------------------------------------
// Kernel 3: per-anchor loss + final reduce.  128 blocks x 256 threads; each
// 16-lane group handles one anchor.  One atomicAdd per block + ticket; last
// block writes out[0].
// ---------------------------------------------------------------------------
__global__ void loss_kernel(const float* __restrict__ part_s,
                            const float* __restrict__ pos_sim,
                            const int* __restrict__ counts,
                            float* __restrict__ loss_acc,
                            unsigned int* __restrict__ ticket,
                            float* __restrict__ out) {
  const int tid = threadIdx.x;
  const int b   = blockIdx.x * 16 + (tid >> 4);
  const int sub = tid & 15;
  const float* ps = part_s + (size_t)b * NTILES;
  float s = 0.0f;
#pragma unroll
  for (int i = 0; i < NTILES / 16; i++) s += ps[sub + i * 16];
  s += __shfl_xor(s, 1, 64);
  s += __shfl_xor(s, 2, 64);
  s += __shfl_xor(s, 4, 64);
  s += __shfl_xor(s, 8, 64);   // 16-lane group now holds full S

  float acc = 0.0f;
  if (sub == 0) {
    float L = logf(s);  // neg_lse in natural-log units
    float p0 = pos_sim[b * P + 0], p1 = pos_sim[b * P + 1];
    float p2 = pos_sim[b * P + 2], p3 = pos_sim[b * P + 3];
    int cnt = counts[b];
    float pj[P] = {p0, p1, p2, p3};
#pragma unroll
    for (int jj = 0; jj < P; jj++) {
      if (jj < cnt) {
        float hi = fmaxf(pj[jj], L), lo = fminf(pj[jj], L);
        acc += hi + log1pf(__expf(lo - hi)) - pj[jj];
      }
    }
    float mp = fmaxf(fmaxf(p0, p1), fmaxf(p2, p3));
    float e0 = __expf(p0 - mp), e1 = __expf(p1 - mp);
    float e2 = __expf(p2 - mp), e3 = __expf(p3 - mp);
    float se = e0 + e1 + e2 + e3;
    float wps = (e0 * p0 + e1 * p1 + e2 * p2 + e3 * p3) / se;
    if (cnt > 1) {
      float hi = fmaxf(wps, L), lo = fminf(wps, L);
      acc += ALPHA * (hi + log1pf(__expf(lo - hi)) - wps);
    }
  }
#pragma unroll
  for (int off = 32; off > 0; off >>= 1) acc += __shfl_xor(acc, off, 64);
  __shared__ float sa[4];
  int wid = tid >> 6, lane = tid & 63;
  if (lane == 0) sa[wid] = acc;
  __syncthreads();
  if (tid == 0) {
    atomicAdd(loss_acc, sa[0] + sa[1] + sa[2] + sa[3]);
    __threadfence();
    unsigned int t = atomicAdd(ticket, 1u);
    if (t == (unsigned int)gridDim.x - 1u) {
      float total = atomicAdd(loss_acc, 0.0f);  // atomic read-back
      out[0] = total / (float)B;
    }
  }
}

// ---------------------------------------------------------------------------
extern "C" void kernel_launch(void* const* d_in, const int* in_sizes, int n_in,
                              void* d_out, int out_size, void* d_ws,
                              size_t ws_size, hipStream_t stream) {
  const float* anc    = (const float*)d_in[0];
  const float* pos    = (const float*)d_in[1];
  const float* neg    = (const float*)d_in[2];
  const int*   counts = (const int*)d_in[3];
  float* out = (float*)d_out;

  // Workspace layout: ~12.6 MB
  unsigned char* a_f8 = (unsigned char*)d_ws;            // B*D      (0.5 MB)
  unsigned char* n_f8 = a_f8 + (size_t)B * D;            // NNEG*D   (8 MB)
  float* part_s  = (float*)(n_f8 + (size_t)NNEG * D);    // B*NTILES (4 MB)
  float* pos_sim = part_s + (size_t)B * NTILES;          // B*P
  float* loss_acc = pos_sim + B * P;                     // 1
  unsigned int* ticket = (unsigned int*)(loss_acc + 1);  // 1

  // 2176 panel blocks + 2048 possim blocks
  prep_kernel<<<NPANEL + B * P / 4, 256, 0, stream>>>(
      anc, pos, neg, a_f8, n_f8, pos_sim, loss_acc, ticket);

  negsim_mfma_kernel<<<4096, 256, 0, stream>>>(a_f8, n_f8, part_s);

  loss_kernel<<<B / 16, 256, 0, stream>>>(part_s, pos_sim, counts,
                                          loss_acc, ticket, out);
}

// Round 3
// 143.116 us; speedup vs baseline: 1.2542x; 1.2542x over previous
//
#include <hip/hip_runtime.h>
#include <math.h>

// Problem constants (match reference)
constexpr int   B       = 2048;
constexpr int   P       = 4;
constexpr int   D       = 256;       // K of the GEMM
constexpr int   NNEG    = 32768;
constexpr int   NTILES  = NNEG / 64; // per-row exp2-sum partials (64-col patches)
constexpr float TEMP    = 0.05f;
constexpr float ALPHA   = 0.1f;
constexpr float EPS     = 1e-12f;
constexpr float INV_T   = 1.0f / TEMP;
// A-side rows are pre-scaled by (1/T)*log2(e) so the MFMA accumulator is
// directly q = sim/T * log2(e), and exp(sim/T) = exp2(q).  |q| <= ~30 so no
// max-tracking is needed, and 28.85 << 448 (fp8 e4m3 max) so the scale is
// fp8-safe; fp relative precision is scale-invariant.
constexpr float SCALE_Q = 28.853900817779268f;

typedef float f32x4 __attribute__((ext_vector_type(4)));
typedef int   i32x8 __attribute__((ext_vector_type(8)));

// fp32 -> bf16 (RNE), bit-level
__device__ inline unsigned short f2bf(float f) {
  unsigned int u = __float_as_uint(f);
  u = (u + 0x7fffu + ((u >> 16) & 1u)) >> 16;
  return (unsigned short)u;
}
// bf16 bits -> fp32
__device__ inline float bf2f(unsigned short u) {
  return __uint_as_float((unsigned int)u << 16);
}

// ---------------------------------------------------------------------------
// FP8 FRAGMENT-MAJOR layout: element (row, k) of a [R x 256] fp8 matrix is at
// BYTE index  p*4096 + c*512 + q*128 + r*8 + j
// where p=row>>4 (16-row panel, 4096 B contiguous), r=row&15, c=k>>5
// (32-k chunk), q=(k>>3)&3, j=k&7.  Fragment (p,c) = 512 contiguous bytes;
// lane l=r+16t reads its 8 B at byte offset l*8.  k identically permuted for
// A and B, so any consistent chunk ordering fed to the MFMA is exact (the
// MFMA pairs A and B operand byte positions identically; we never need the
// HW's internal byte->k bijection).
// ---------------------------------------------------------------------------

// ---------------------------------------------------------------------------
// Kernel 1 (fused prep) — UNCHANGED from the verified 126us version.
// ---------------------------------------------------------------------------
constexpr int NPANEL = (B + NNEG) / 16;      // 2176
constexpr int LSTR   = 264;                  // LDS row stride in ushorts

__global__ __launch_bounds__(256) void prep_kernel(
    const float* __restrict__ a,
    const float* __restrict__ pzx,
    const float* __restrict__ n,
    unsigned char* __restrict__ a_f8,
    unsigned char* __restrict__ n_f8,
    float* __restrict__ pos_sim,
    float* __restrict__ loss_acc,
    unsigned int* __restrict__ ticket) {
  if (blockIdx.x == 0 && threadIdx.x == 0) { *loss_acc = 0.0f; *ticket = 0u; }
  const int id   = blockIdx.x;
  const int tid  = threadIdx.x;
  const int wave = tid >> 6;
  const int lane = tid & 63;

  if (id < NPANEL) {
    __shared__ __align__(16) unsigned short sm[16 * LSTR];
    const float* src; unsigned char* dst; int prow; float post;
    if (id < B / 16) { src = a; dst = a_f8; prow = id;          post = SCALE_Q; }
    else             { src = n; dst = n_f8; prow = id - B / 16; post = 1.0f; }

    // Phase 1: normalize rows into LDS (bf16).
#pragma unroll
    for (int rr = 0; rr < 4; rr++) {
      const int r = wave * 4 + rr;                       // 0..15
      float4 v = ((const float4*)(src + ((size_t)prow * 16 + r) * D))[lane];
      float ss = v.x * v.x + v.y * v.y + v.z * v.z + v.w * v.w;
#pragma unroll
      for (int off = 32; off > 0; off >>= 1) ss += __shfl_xor(ss, off, 64);
      float inv = post / fmaxf(sqrtf(ss), EPS);
      ushort4 o;
      o.x = f2bf(v.x * inv); o.y = f2bf(v.y * inv);
      o.z = f2bf(v.z * inv); o.w = f2bf(v.w * inv);
      *(ushort4*)&sm[r * LSTR + lane * 4] = o;
    }
    __syncthreads();

    // Phase 2: thread t emits fp8 panel bytes [t*16,+16) as one uint4 store.
    const int r1 = (2 * tid) & 15;
    const int r2 = (2 * tid + 1) & 15;
    const int k0 = (tid >> 5) * 32 + ((tid >> 3) & 3) * 8;
    const unsigned short* s1 = &sm[r1 * LSTR + k0];
    const unsigned short* s2 = &sm[r2 * LSTR + k0];
    uint4 ov;
    {
      int w0 = __builtin_amdgcn_cvt_pk_fp8_f32(bf2f(s1[0]), bf2f(s1[1]), 0, false);
      w0     = __builtin_amdgcn_cvt_pk_fp8_f32(bf2f(s1[2]), bf2f(s1[3]), w0, true);
      int w1 = __builtin_amdgcn_cvt_pk_fp8_f32(bf2f(s1[4]), bf2f(s1[5]), 0, false);
      w1     = __builtin_amdgcn_cvt_pk_fp8_f32(bf2f(s1[6]), bf2f(s1[7]), w1, true);
      int w2 = __builtin_amdgcn_cvt_pk_fp8_f32(bf2f(s2[0]), bf2f(s2[1]), 0, false);
      w2     = __builtin_amdgcn_cvt_pk_fp8_f32(bf2f(s2[2]), bf2f(s2[3]), w2, true);
      int w3 = __builtin_amdgcn_cvt_pk_fp8_f32(bf2f(s2[4]), bf2f(s2[5]), 0, false);
      w3     = __builtin_amdgcn_cvt_pk_fp8_f32(bf2f(s2[6]), bf2f(s2[7]), w3, true);
      ov.x = (unsigned)w0; ov.y = (unsigned)w1;
      ov.z = (unsigned)w2; ov.w = (unsigned)w3;
    }
    *(uint4*)(dst + (size_t)prow * 4096 + tid * 16) = ov;
  } else {
    int pw = (id - NPANEL) * 4 + wave;   // 0..B*P-1
    if (pw >= B * P) return;
    int b = pw >> 2;                     // P == 4
    float4 av = ((const float4*)(a + (size_t)b * D))[lane];
    float4 pv = ((const float4*)(pzx + (size_t)pw * D))[lane];
    float d  = av.x * pv.x + av.y * pv.y + av.z * pv.z + av.w * pv.w;
    float sa = av.x * av.x + av.y * av.y + av.z * av.z + av.w * av.w;
    float sp = pv.x * pv.x + pv.y * pv.y + pv.z * pv.z + pv.w * pv.w;
#pragma unroll
    for (int off = 32; off > 0; off >>= 1) {
      d  += __shfl_xor(d, off, 64);
      sa += __shfl_xor(sa, off, 64);
      sp += __shfl_xor(sp, off, 64);
    }
    if (lane == 0) {
      float inva = 1.0f / fmaxf(sqrtf(sa), EPS);
      float invp = 1.0f / fmaxf(sqrtf(sp), EPS);
      pos_sim[pw] = d * inva * invp * INV_T;
    }
  }
}

// ---------------------------------------------------------------------------
// Kernel 2: MX-scaled fp8 MFMA GEMM (mfma_scale_f32_16x16x128_f8f6f4, unit
// e8m0 scales = bit-identical fp8 math at 2x the non-scaled fp8 rate) fused
// with exp2-sum partials.
// Register-budget design: 512 threads / 8 waves, wave tile 64x32
// (acc = 4x2 f32x4 = 32 regs).  Peak live = acc 32 + af[4] 32 +
// bf0[2]+bf1[2] 32 + addr ~12 < 128 unified VGPR budget at
// launch_bounds(512,4) (2 blocks/CU, 16 waves/CU).
// Waves own disjoint 32-col patches -> B traffic 64 KB/block (L2 floor
// ~7.4us, balanced with the ~7.4us MX MFMA floor).
// WORKSPACE-COMPAT epilogue: wave pairs combine their 32-col partials via a
// 2 KB LDS buffer so part_s keeps the PROVEN layout [row][NTILES=512]
// (64-col granularity, 4 MB) — total workspace identical to the 126us
// kernel (~12.6 MB); the 16.6 MB variant is what faulted the container.
// XCD swizzle: id&7 -> xcd owns 16-nblk strip (1 MB N fp8) + A (0.5 MB).
// ---------------------------------------------------------------------------
constexpr int BM = 64, BN = 256;

__global__ __launch_bounds__(512, 4) void negsim_mfma_kernel(
    const unsigned char* __restrict__ Af,   // fp8 frag-major [B][256]
    const unsigned char* __restrict__ Nf,   // fp8 frag-major [NNEG][256]
    float* __restrict__ part_s) {           // [B][NTILES]
  __shared__ __align__(16) unsigned char As[32 * 512];  // 16 KB
  __shared__ float part_l[8][64];                       // 2 KB combine buffer

  const int tid  = threadIdx.x;
  const int wave = tid >> 6;   // 0..7 = N-direction 32-col patch
  const int lane = tid & 63;

  const int id   = blockIdx.x;
  const int xcd  = id & 7;
  const int j    = id >> 3;              // 0..511
  const int nblk = xcd * 16 + (j & 15);  // 0..127
  const int mblk = j >> 4;               // 0..31
  const int m0   = mblk * BM;
  const int n0   = nblk * BN;

  // ---- stage A-tile once (16 KB contiguous in global AND LDS):
  //      8 waves x 2 instr, each 1 KB. ----
#pragma unroll
  for (int t = 0; t < 2; t++) {
    const int s = wave * 2 + t;
    __builtin_amdgcn_global_load_lds(
        (const __attribute__((address_space(1))) unsigned int*)
            (Af + (size_t)(m0 >> 4) * 4096 + s * 1024 + lane * 16),
        (__attribute__((address_space(3))) unsigned int*)(As + s * 1024 + lane * 16),
        16, 0, 0);
  }

  // ---- B loads: wave w owns cols [n0+w*32, +32) = panels (n0>>4)+2w, +2w+1.
  //      Load BOTH K-halves before any MFMA (h=1 latency hides under h=0).
  const unsigned char* Bp = Nf + (size_t)((n0 >> 4) + wave * 2) * 4096 + lane * 8;

  i32x8 bf0[2], bf1[2];
#pragma unroll
  for (int ni = 0; ni < 2; ni++) {
#pragma unroll
    for (int q = 0; q < 4; q++) {
      int2 v = *(const int2*)(Bp + (size_t)ni * 4096 + q * 512);
      bf0[ni][2 * q]     = v.x;
      bf0[ni][2 * q + 1] = v.y;
    }
#pragma unroll
    for (int q = 0; q < 4; q++) {
      int2 v = *(const int2*)(Bp + (size_t)ni * 4096 + (4 + q) * 512);
      bf1[ni][2 * q]     = v.x;
      bf1[ni][2 * q + 1] = v.y;
    }
  }

  __syncthreads();   // drains the A staging (barrier implies vmcnt(0))

  f32x4 acc[4][2] = {};

  // ---- K half h=0: af from LDS (b64 reads, 2-way bank alias = free) ----
  {
    i32x8 af[4];
#pragma unroll
    for (int mi = 0; mi < 4; mi++)
#pragma unroll
      for (int q = 0; q < 4; q++) {
        int2 v = *(const int2*)&As[(mi * 8 + q) * 512 + lane * 8];
        af[mi][2 * q]     = v.x;
        af[mi][2 * q + 1] = v.y;
      }
#pragma unroll
    for (int mi = 0; mi < 4; mi++)
#pragma unroll
      for (int ni = 0; ni < 2; ni++)
        acc[mi][ni] = __builtin_amdgcn_mfma_scale_f32_16x16x128_f8f6f4(
            af[mi], bf0[ni], acc[mi][ni],
            0, 0,                       // cbsz/blgp: FP8 e4m3 for A and B
            0, 0x7f7f7f7f,              // scale_a = 1.0 (e8m0 127)
            0, 0x7f7f7f7f);             // scale_b = 1.0
  }

  // ---- K half h=1 ----
  {
    i32x8 af[4];
#pragma unroll
    for (int mi = 0; mi < 4; mi++)
#pragma unroll
      for (int q = 0; q < 4; q++) {
        int2 v = *(const int2*)&As[(mi * 8 + 4 + q) * 512 + lane * 8];
        af[mi][2 * q]     = v.x;
        af[mi][2 * q + 1] = v.y;
      }
#pragma unroll
    for (int mi = 0; mi < 4; mi++)
#pragma unroll
      for (int ni = 0; ni < 2; ni++)
        acc[mi][ni] = __builtin_amdgcn_mfma_scale_f32_16x16x128_f8f6f4(
            af[mi], bf1[ni], acc[mi][ni],
            0, 0,
            0, 0x7f7f7f7f,
            0, 0x7f7f7f7f);
  }

  // ---- Epilogue.  C/D layout row = mi*16 + (lane>>4)*4 + rr,
  //      col = ni*16+(lane&15) (shape-determined on gfx950).
  //      Stage per-wave 32-col partials in LDS, combine wave pairs to the
  //      proven 64-col part_s granularity. ----
#pragma unroll
  for (int mi = 0; mi < 4; mi++) {
#pragma unroll
    for (int rr = 0; rr < 4; rr++) {
      float s = __builtin_amdgcn_exp2f(acc[mi][0][rr]) +
                __builtin_amdgcn_exp2f(acc[mi][1][rr]);
#pragma unroll
      for (int off = 1; off < 16; off <<= 1) s += __shfl_xor(s, off, 64);
      if ((lane & 15) == 0)
        part_l[wave][mi * 16 + (lane >> 4) * 4 + rr] = s;
    }
  }
  __syncthreads();
  if (tid < 256) {
    const int u   = tid >> 6;    // 0..3 : 64-col patch within the block
    const int row = tid & 63;
    float s64 = part_l[2 * u][row] + part_l[2 * u + 1][row];
    part_s[(size_t)(m0 + row) * NTILES + (nblk * 4 + u)] = s64;
  }
}

// ---------------------------------------------------------------------------
// Kernel 3: per-anchor loss + final reduce — UNCHANGED from the verified
// version (NTILES=512 layout).
// ---------------------------------------------------------------------------
__global__ void loss_kernel(const float* __restrict__ part_s,
                            const float* __restrict__ pos_sim,
                            const int* __restrict__ counts,
                            float* __restrict__ loss_acc,
                            unsigned int* __restrict__ ticket,
                            float* __restrict__ out) {
  const int tid = threadIdx.x;
  const int b   = blockIdx.x * 16 + (tid >> 4);
  const int sub = tid & 15;
  const float* ps = part_s + (size_t)b * NTILES;
  float s = 0.0f;
#pragma unroll
  for (int i = 0; i < NTILES / 16; i++) s += ps[sub + i * 16];
  s += __shfl_xor(s, 1, 64);
  s += __shfl_xor(s, 2, 64);
  s += __shfl_xor(s, 4, 64);
  s += __shfl_xor(s, 8, 64);   // 16-lane group now holds full S

  float acc = 0.0f;
  if (sub == 0) {
    float L = logf(s);  // neg_lse in natural-log units
    float p0 = pos_sim[b * P + 0], p1 = pos_sim[b * P + 1];
    float p2 = pos_sim[b * P + 2], p3 = pos_sim[b * P + 3];
    int cnt = counts[b];
    float pj[P] = {p0, p1, p2, p3};
#pragma unroll
    for (int jj = 0; jj < P; jj++) {
      if (jj < cnt) {
        float hi = fmaxf(pj[jj], L), lo = fminf(pj[jj], L);
        acc += hi + log1pf(__expf(lo - hi)) - pj[jj];
      }
    }
    float mp = fmaxf(fmaxf(p0, p1), fmaxf(p2, p3));
    float e0 = __expf(p0 - mp), e1 = __expf(p1 - mp);
    float e2 = __expf(p2 - mp), e3 = __expf(p3 - mp);
    float se = e0 + e1 + e2 + e3;
    float wps = (e0 * p0 + e1 * p1 + e2 * p2 + e3 * p3) / se;
    if (cnt > 1) {
      float hi = fmaxf(wps, L), lo = fminf(wps, L);
      acc += ALPHA * (hi + log1pf(__expf(lo - hi)) - wps);
    }
  }
#pragma unroll
  for (int off = 32; off > 0; off >>= 1) acc += __shfl_xor(acc, off, 64);
  __shared__ float sa[4];
  int wid = tid >> 6, lane = tid & 63;
  if (lane == 0) sa[wid] = acc;
  __syncthreads();
  if (tid == 0) {
    atomicAdd(loss_acc, sa[0] + sa[1] + sa[2] + sa[3]);
    __threadfence();
    unsigned int t = atomicAdd(ticket, 1u);
    if (t == (unsigned int)gridDim.x - 1u) {
      float total = atomicAdd(loss_acc, 0.0f);  // atomic read-back
      out[0] = total / (float)B;
    }
  }
}

// ---------------------------------------------------------------------------
extern "C" void kernel_launch(void* const* d_in, const int* in_sizes, int n_in,
                              void* d_out, int out_size, void* d_ws,
                              size_t ws_size, hipStream_t stream) {
  const float* anc    = (const float*)d_in[0];
  const float* pos    = (const float*)d_in[1];
  const float* neg    = (const float*)d_in[2];
  const int*   counts = (const int*)d_in[3];
  float* out = (float*)d_out;

  // Workspace layout: ~12.6 MB (identical to the verified 126us kernel)
  unsigned char* a_f8 = (unsigned char*)d_ws;            // B*D      (0.5 MB)
  unsigned char* n_f8 = a_f8 + (size_t)B * D;            // NNEG*D   (8 MB)
  float* part_s  = (float*)(n_f8 + (size_t)NNEG * D);    // B*NTILES (4 MB)
  float* pos_sim = part_s + (size_t)B * NTILES;          // B*P
  float* loss_acc = pos_sim + B * P;                     // 1
  unsigned int* ticket = (unsigned int*)(loss_acc + 1);  // 1

  // 2176 panel blocks + 2048 possim blocks
  prep_kernel<<<NPANEL + B * P / 4, 256, 0, stream>>>(
      anc, pos, neg, a_f8, n_f8, pos_sim, loss_acc, ticket);

  negsim_mfma_kernel<<<4096, 512, 0, stream>>>(a_f8, n_f8, part_s);

  loss_kernel<<<B / 16, 256, 0, stream>>>(part_s, pos_sim, counts,
                                          loss_acc, ticket, out);
}

// Round 5
// 121.289 us; speedup vs baseline: 1.4799x; 1.1800x over previous
//
#include <hip/hip_runtime.h>
#include <math.h>

// Problem constants (match reference)
constexpr int   B       = 2048;
constexpr int   P       = 4;
constexpr int   D       = 256;       // K of the GEMM
constexpr int   NNEG    = 32768;
constexpr int   NTILES  = NNEG / 64; // per-row exp2-sum partials (64-col patches)
constexpr float TEMP    = 0.05f;
constexpr float ALPHA   = 0.1f;
constexpr float EPS     = 1e-12f;
constexpr float INV_T   = 1.0f / TEMP;
// A-side rows are pre-scaled by (1/T)*log2(e) so the MFMA accumulator is
// directly q = sim/T * log2(e), and exp(sim/T) = exp2(q).  |q| <= ~30 so no
// max-tracking is needed, and 28.85 << 448 (fp8 e4m3 max) so the scale is
// fp8-safe; fp relative precision is scale-invariant.
constexpr float SCALE_Q = 28.853900817779268f;

typedef float f32x4 __attribute__((ext_vector_type(4)));
typedef int   i32x8 __attribute__((ext_vector_type(8)));

// fp32 -> bf16 (RNE), bit-level
__device__ inline unsigned short f2bf(float f) {
  unsigned int u = __float_as_uint(f);
  u = (u + 0x7fffu + ((u >> 16) & 1u)) >> 16;
  return (unsigned short)u;
}
// bf16 bits -> fp32
__device__ inline float bf2f(unsigned short u) {
  return __uint_as_float((unsigned int)u << 16);
}

// Full 16-lane-row sum via 4 ROW_ROR DPP steps (VALU pipe only, no LDS).
// DPP ctrl must be a LITERAL constant (compiler-enforced), hence the
// hand-unrolled sequence: 0x121=ror1, 0x122=ror2, 0x124=ror4, 0x128=ror8.
__device__ inline float ror16_add(float v) {
  int x;
  x = __builtin_amdgcn_update_dpp(0, __float_as_int(v), 0x121, 0xf, 0xf, true);
  v += __int_as_float(x);
  x = __builtin_amdgcn_update_dpp(0, __float_as_int(v), 0x122, 0xf, 0xf, true);
  v += __int_as_float(x);
  x = __builtin_amdgcn_update_dpp(0, __float_as_int(v), 0x124, 0xf, 0xf, true);
  v += __int_as_float(x);
  x = __builtin_amdgcn_update_dpp(0, __float_as_int(v), 0x128, 0xf, 0xf, true);
  v += __int_as_float(x);
  return v;
}

// ---------------------------------------------------------------------------
// FP8 LANE-MAJOR layout: element (row, k) of a [R x 256] fp8 matrix is at
// BYTE index  p*4096 + h*2048 + t*512 + r*32 + b
// where p=row>>4 (16-row panel, 4096 B contiguous), r=row&15, h=k>>7
// (K=128 half), t=(k>>5)&3 (lane k-group), b=k&31.
// MFMA 16x16x128 lane l = r + 16t reads its 32 operand bytes CONTIGUOUSLY at
// half_base + l*32 (since t*512 + r*32 == l*32).  A and B use the identical
// (row,k)->byte bijection, so the MFMA pairs A/B k-positions consistently and
// the dot product is exact for any internal HW byte->k mapping (same
// principle the round-3 kernel verified with absmax 0.0).
// ---------------------------------------------------------------------------

// ---------------------------------------------------------------------------
// Kernel 1 (fused prep).  Two block ranges:
//  [0, NPANEL): one block per 16-row panel.  Phase 1: wave w normalizes rows
//    w*4..w*4+3 into an LDS bf16 tile (stride 264).  Phase 2 (after barrier):
//    thread t converts to fp8 and writes panel BYTES [t*16,+16) — the 4 KB
//    fp8 panel image is one contiguous coalesced stream.  With the lane-major
//    layout thread t's 16 bytes are 16 CONSECUTIVE k of one row.
//  [NPANEL, ...): possim, one wave per (b,j) pair, exact fp32.
// ---------------------------------------------------------------------------
constexpr int NPANEL = (B + NNEG) / 16;      // 2176
constexpr int LSTR   = 264;                  // LDS row stride in ushorts

__global__ __launch_bounds__(256) void prep_kernel(
    const float* __restrict__ a,
    const float* __restrict__ pzx,
    const float* __restrict__ n,
    unsigned char* __restrict__ a_f8,
    unsigned char* __restrict__ n_f8,
    float* __restrict__ pos_sim,
    float* __restrict__ loss_acc,
    unsigned int* __restrict__ ticket) {
  if (blockIdx.x == 0 && threadIdx.x == 0) { *loss_acc = 0.0f; *ticket = 0u; }
  const int id   = blockIdx.x;
  const int tid  = threadIdx.x;
  const int wave = tid >> 6;
  const int lane = tid & 63;

  if (id < NPANEL) {
    __shared__ __align__(16) unsigned short sm[16 * LSTR];
    const float* src; unsigned char* dst; int prow; float post;
    if (id < B / 16) { src = a; dst = a_f8; prow = id;          post = SCALE_Q; }
    else             { src = n; dst = n_f8; prow = id - B / 16; post = 1.0f; }

    // Phase 1: normalize rows into LDS (bf16).
#pragma unroll
    for (int rr = 0; rr < 4; rr++) {
      const int r = wave * 4 + rr;                       // 0..15
      float4 v = ((const float4*)(src + ((size_t)prow * 16 + r) * D))[lane];
      float ss = v.x * v.x + v.y * v.y + v.z * v.z + v.w * v.w;
#pragma unroll
      for (int off = 32; off > 0; off >>= 1) ss += __shfl_xor(ss, off, 64);
      float inv = post / fmaxf(sqrtf(ss), EPS);
      ushort4 o;
      o.x = f2bf(v.x * inv); o.y = f2bf(v.y * inv);
      o.z = f2bf(v.z * inv); o.w = f2bf(v.w * inv);
      *(ushort4*)&sm[r * LSTR + lane * 4] = o;
    }
    __syncthreads();

    // Phase 2: thread t emits fp8 panel bytes [t*16,+16) as one uint4 store.
    // Byte o: h=o>>11, t2=(o>>9)&3, r=(o>>5)&15, b=o&31; k = h*128+t2*32+b.
    // For o = tid*16: one row r, 16 consecutive k starting at k0.
    const int o  = tid * 16;
    const int r  = (o >> 5) & 15;
    const int k0 = (o >> 11) * 128 + ((o >> 9) & 3) * 32 + (o & 31);
    const unsigned short* s1 = &sm[r * LSTR + k0];   // 16 consecutive bf16
    uint4 ov;
    {
      int w0 = __builtin_amdgcn_cvt_pk_fp8_f32(bf2f(s1[0]),  bf2f(s1[1]),  0,  false);
      w0     = __builtin_amdgcn_cvt_pk_fp8_f32(bf2f(s1[2]),  bf2f(s1[3]),  w0, true);
      int w1 = __builtin_amdgcn_cvt_pk_fp8_f32(bf2f(s1[4]),  bf2f(s1[5]),  0,  false);
      w1     = __builtin_amdgcn_cvt_pk_fp8_f32(bf2f(s1[6]),  bf2f(s1[7]),  w1, true);
      int w2 = __builtin_amdgcn_cvt_pk_fp8_f32(bf2f(s1[8]),  bf2f(s1[9]),  0,  false);
      w2     = __builtin_amdgcn_cvt_pk_fp8_f32(bf2f(s1[10]), bf2f(s1[11]), w2, true);
      int w3 = __builtin_amdgcn_cvt_pk_fp8_f32(bf2f(s1[12]), bf2f(s1[13]), 0,  false);
      w3     = __builtin_amdgcn_cvt_pk_fp8_f32(bf2f(s1[14]), bf2f(s1[15]), w3, true);
      ov.x = (unsigned)w0; ov.y = (unsigned)w1;
      ov.z = (unsigned)w2; ov.w = (unsigned)w3;
    }
    *(uint4*)(dst + (size_t)prow * 4096 + tid * 16) = ov;
  } else {
    int pw = (id - NPANEL) * 4 + wave;   // 0..B*P-1
    if (pw >= B * P) return;
    int b = pw >> 2;                     // P == 4
    float4 av = ((const float4*)(a + (size_t)b * D))[lane];
    float4 pv = ((const float4*)(pzx + (size_t)pw * D))[lane];
    float d  = av.x * pv.x + av.y * pv.y + av.z * pv.z + av.w * pv.w;
    float sa = av.x * av.x + av.y * av.y + av.z * av.z + av.w * av.w;
    float sp = pv.x * pv.x + pv.y * pv.y + pv.z * pv.z + pv.w * pv.w;
#pragma unroll
    for (int off = 32; off > 0; off >>= 1) {
      d  += __shfl_xor(d, off, 64);
      sa += __shfl_xor(sa, off, 64);
      sp += __shfl_xor(sp, off, 64);
    }
    if (lane == 0) {
      float inva = 1.0f / fmaxf(sqrtf(sa), EPS);
      float invp = 1.0f / fmaxf(sqrtf(sp), EPS);
      pos_sim[pw] = d * inva * invp * INV_T;
    }
  }
}

// ---------------------------------------------------------------------------
// Kernel 2: MX-scaled fp8 MFMA GEMM (mfma_scale_f32_16x16x128_f8f6f4, unit
// e8m0 scales = bit-identical fp8 math at 2x the non-scaled fp8 rate) fused
// with exp2-sum partials.
// LEAN-SCAFFOLDING redesign vs round 3 (which was issue-bound at MfmaUtil
// 12%: 32 ds_read_b64 + 64 ds_bpermute shuffles per wave dwarfed the 16
// MFMAs):
//  * lane-major fp8 layout -> A fragment = ONE 32-B LDS read (2x b128);
//    8 b128 LDS reads/wave total (was 32 b64 + 64 bpermute LDS-pipe ops).
//  * B operand = i32x8 global load (2x dwordx4); 8 VMEM loads/wave (was 16).
//  * epilogue 16-lane reduction via DPP ROW_ROR adds (VALU pipe, zero LDS).
// 512 threads / 8 waves, wave tile 64x32, acc = 32 regs; peak live
// ~ acc32 + bf32 + af8 + addr ~ 90 < 128 cap at launch_bounds(512,4).
// One barrier before compute (drains A staging + keeps B loads early).
// part_s keeps the PROVEN [row][NTILES=512] 64-col layout via the 2 KB LDS
// pair-combine (workspace identical to the verified 126us kernel, ~12.6 MB).
// XCD swizzle: id&7 -> xcd owns 16-nblk strip (1 MB N fp8) + A (0.5 MB).
// ---------------------------------------------------------------------------
constexpr int BM = 64, BN = 256;

__global__ __launch_bounds__(512, 4) void negsim_mfma_kernel(
    const unsigned char* __restrict__ Af,   // fp8 lane-major [B][256]
    const unsigned char* __restrict__ Nf,   // fp8 lane-major [NNEG][256]
    float* __restrict__ part_s) {           // [B][NTILES]
  __shared__ __align__(16) unsigned char As[4 * 4096];  // 16 KB (4 panels)
  __shared__ float part_l[8][64];                       // 2 KB combine buffer

  const int tid  = threadIdx.x;
  const int wave = tid >> 6;   // 0..7 = N-direction 32-col patch
  const int lane = tid & 63;

  const int id   = blockIdx.x;
  const int xcd  = id & 7;
  const int j    = id >> 3;              // 0..511
  const int nblk = xcd * 16 + (j & 15);  // 0..127
  const int mblk = j >> 4;               // 0..31
  const int m0   = mblk * BM;
  const int n0   = nblk * BN;

  // ---- stage A-tile once (16 KB, linear in global AND LDS):
  //      8 waves x 2 instr, each 1 KB. ----
#pragma unroll
  for (int t = 0; t < 2; t++) {
    const int s = wave * 2 + t;
    __builtin_amdgcn_global_load_lds(
        (const __attribute__((address_space(1))) unsigned int*)
            (Af + (size_t)(m0 >> 4) * 4096 + s * 1024 + lane * 16),
        (__attribute__((address_space(3))) unsigned int*)(As + s * 1024 + lane * 16),
        16, 0, 0);
  }

  // ---- B loads: wave w owns cols [n0+w*32,+32) = panels (n0>>4)+2w, +2w+1.
  //      Lane l's 32-B operand is contiguous at half_base + l*32; load both
  //      K-halves of both panels up-front (4 x i32x8 = 8 dwordx4). ----
  const unsigned char* Bp = Nf + (size_t)((n0 >> 4) + wave * 2) * 4096 + lane * 32;

  i32x8 bf[2][2];   // [ni][h]
#pragma unroll
  for (int ni = 0; ni < 2; ni++)
#pragma unroll
    for (int h = 0; h < 2; h++)
      bf[ni][h] = *(const i32x8*)(Bp + (size_t)ni * 4096 + h * 2048);

  __syncthreads();   // drains the A staging (barrier implies vmcnt(0))

  f32x4 acc[4][2] = {};

#pragma unroll
  for (int h = 0; h < 2; h++) {
#pragma unroll
    for (int mi = 0; mi < 4; mi++) {
      i32x8 af = *(const i32x8*)&As[mi * 4096 + h * 2048 + lane * 32];
#pragma unroll
      for (int ni = 0; ni < 2; ni++)
        acc[mi][ni] = __builtin_amdgcn_mfma_scale_f32_16x16x128_f8f6f4(
            af, bf[ni][h], acc[mi][ni],
            0, 0,                       // cbsz/blgp: FP8 e4m3 for A and B
            0, 0x7f7f7f7f,              // scale_a = 1.0 (e8m0 127)
            0, 0x7f7f7f7f);             // scale_b = 1.0
    }
  }

  // ---- Epilogue.  C/D layout row = mi*16 + (lane>>4)*4 + rr,
  //      col = ni*16+(lane&15) (shape-determined on gfx950; verified).
  //      16-col reduce via DPP ror-adds (VALU only), stage per-wave 32-col
  //      partials in LDS, combine wave pairs to the proven 64-col
  //      granularity. ----
#pragma unroll
  for (int mi = 0; mi < 4; mi++) {
#pragma unroll
    for (int rr = 0; rr < 4; rr++) {
      float e = __builtin_amdgcn_exp2f(acc[mi][0][rr]) +
                __builtin_amdgcn_exp2f(acc[mi][1][rr]);
      e = ror16_add(e);   // every lane of the 16-lane row now holds the sum
      if ((lane & 15) == 0)
        part_l[wave][mi * 16 + (lane >> 4) * 4 + rr] = e;
    }
  }
  __syncthreads();
  if (tid < 256) {
    const int u   = tid >> 6;    // 0..3 : 64-col patch within the block
    const int row = tid & 63;
    float s64 = part_l[2 * u][row] + part_l[2 * u + 1][row];
    part_s[(size_t)(m0 + row) * NTILES + (nblk * 4 + u)] = s64;
  }
}

// ---------------------------------------------------------------------------
// Kernel 3: per-anchor loss + final reduce — UNCHANGED from the verified
// version (NTILES=512 layout).
// ---------------------------------------------------------------------------
__global__ void loss_kernel(const float* __restrict__ part_s,
                            const float* __restrict__ pos_sim,
                            const int* __restrict__ counts,
                            float* __restrict__ loss_acc,
                            unsigned int* __restrict__ ticket,
                            float* __restrict__ out) {
  const int tid = threadIdx.x;
  const int b   = blockIdx.x * 16 + (tid >> 4);
  const int sub = tid & 15;
  const float* ps = part_s + (size_t)b * NTILES;
  float s = 0.0f;
#pragma unroll
  for (int i = 0; i < NTILES / 16; i++) s += ps[sub + i * 16];
  s += __shfl_xor(s, 1, 64);
  s += __shfl_xor(s, 2, 64);
  s += __shfl_xor(s, 4, 64);
  s += __shfl_xor(s, 8, 64);   // 16-lane group now holds full S

  float acc = 0.0f;
  if (sub == 0) {
    float L = logf(s);  // neg_lse in natural-log units
    float p0 = pos_sim[b * P + 0], p1 = pos_sim[b * P + 1];
    float p2 = pos_sim[b * P + 2], p3 = pos_sim[b * P + 3];
    int cnt = counts[b];
    float pj[P] = {p0, p1, p2, p3};
#pragma unroll
    for (int jj = 0; jj < P; jj++) {
      if (jj < cnt) {
        float hi = fmaxf(pj[jj], L), lo = fminf(pj[jj], L);
        acc += hi + log1pf(__expf(lo - hi)) - pj[jj];
      }
    }
    float mp = fmaxf(fmaxf(p0, p1), fmaxf(p2, p3));
    float e0 = __expf(p0 - mp), e1 = __expf(p1 - mp);
    float e2 = __expf(p2 - mp), e3 = __expf(p3 - mp);
    float se = e0 + e1 + e2 + e3;
    float wps = (e0 * p0 + e1 * p1 + e2 * p2 + e3 * p3) / se;
    if (cnt > 1) {
      float hi = fmaxf(wps, L), lo = fminf(wps, L);
      acc += ALPHA * (hi + log1pf(__expf(lo - hi)) - wps);
    }
  }
#pragma unroll
  for (int off = 32; off > 0; off >>= 1) acc += __shfl_xor(acc, off, 64);
  __shared__ float sa[4];
  int wid = tid >> 6, lane = tid & 63;
  if (lane == 0) sa[wid] = acc;
  __syncthreads();
  if (tid == 0) {
    atomicAdd(loss_acc, sa[0] + sa[1] + sa[2] + sa[3]);
    __threadfence();
    unsigned int t = atomicAdd(ticket, 1u);
    if (t == (unsigned int)gridDim.x - 1u) {
      float total = atomicAdd(loss_acc, 0.0f);  // atomic read-back
      out[0] = total / (float)B;
    }
  }
}

// ---------------------------------------------------------------------------
extern "C" void kernel_launch(void* const* d_in, const int* in_sizes, int n_in,
                              void* d_out, int out_size, void* d_ws,
                              size_t ws_size, hipStream_t stream) {
  const float* anc    = (const float*)d_in[0];
  const float* pos    = (const float*)d_in[1];
  const float* neg    = (const float*)d_in[2];
  const int*   counts = (const int*)d_in[3];
  float* out = (float*)d_out;

  // Workspace layout: ~12.6 MB (identical to the verified 126us kernel)
  unsigned char* a_f8 = (unsigned char*)d_ws;            // B*D      (0.5 MB)
  unsigned char* n_f8 = a_f8 + (size_t)B * D;            // NNEG*D   (8 MB)
  float* part_s  = (float*)(n_f8 + (size_t)NNEG * D);    // B*NTILES (4 MB)
  float* pos_sim = part_s + (size_t)B * NTILES;          // B*P
  float* loss_acc = pos_sim + B * P;                     // 1
  unsigned int* ticket = (unsigned int*)(loss_acc + 1);  // 1

  // 2176 panel blocks + 2048 possim blocks
  prep_kernel<<<NPANEL + B * P / 4, 256, 0, stream>>>(
      anc, pos, neg, a_f8, n_f8, pos_sim, loss_acc, ticket);

  negsim_mfma_kernel<<<4096, 512, 0, stream>>>(a_f8, n_f8, part_s);

  loss_kernel<<<B / 16, 256, 0, stream>>>(part_s, pos_sim, counts,
                                          loss_acc, ticket, out);
}